// Round 1
// baseline (577.989 us; speedup 1.0000x reference)
//
#include <hip/hip_runtime.h>
#include <hip/hip_bf16.h>

typedef __attribute__((ext_vector_type(8))) short short8;   // 8 bf16 (4 VGPRs) — MFMA A/B frag
typedef __attribute__((ext_vector_type(4))) float f32x4;    // MFMA C/D frag

#define DDIM 256
#define WROW 257
#define WSTRIDE 66049  // 257*257

__device__ __forceinline__ unsigned short f2bf(float f) {
    unsigned int u = __float_as_uint(f);
    u += 0x7fff + ((u >> 16) & 1);   // RNE (finite values)
    return (unsigned short)(u >> 16);
}
__device__ __forceinline__ float bf2f(unsigned short s) {
    return __uint_as_float(((unsigned int)s) << 16);
}

// One layer: H[b][n] = x_b^T A_n x_b + x_b . v_n + d_n,  x = X[b][0:256] (f32 in)
// Grid: (2048/64 row-tiles, 256 n). Block: 256 thr = 4 waves; wave w owns j-cols [w*64, w*64+64).
__global__ __launch_bounds__(256, 2) void pn_layer_kernel(
    const float* __restrict__ X,    // [2048][256]
    const float* __restrict__ W,    // [256][257][257]
    float* __restrict__ H)          // [2048][256]
{
    __shared__ __align__(16) char Xl[64 * 256 * 2];        // bf16 [row=64][k=256], XOR-swizzled
    __shared__ __align__(16) char Wl[2][256 * 32 * 2];     // bf16 [j=256][k=32] (B^T layout), swizzled, dbuf

    const int tid  = threadIdx.x;
    const int lane = tid & 63;
    const int wv   = tid >> 6;      // j-band 0..3
    const int qw   = lane >> 4;     // 0..3
    const int r15  = lane & 15;

    const int n  = blockIdx.y;
    const int b0 = blockIdx.x * 64;
    const float* Wn = W + (size_t)n * WSTRIDE;

    // ---- stage X tile [64][256] f32 -> bf16 LDS (swizzle: byte ^= (row&7)<<4) ----
    {
        const float4* Xv = reinterpret_cast<const float4*>(X + (size_t)b0 * DDIM);
        #pragma unroll
        for (int it = 0; it < 16; ++it) {
            int idx4 = tid + it * 256;          // 0..4095
            int r = idx4 >> 6, c4 = idx4 & 63;  // row, float4-col
            float4 v = Xv[r * 64 + c4];
            uint2 p;
            p.x = (unsigned)f2bf(v.x) | ((unsigned)f2bf(v.y) << 16);
            p.y = (unsigned)f2bf(v.z) | ((unsigned)f2bf(v.w) << 16);
            int byte = (r * 512 + c4 * 8) ^ ((r & 7) << 4);
            *reinterpret_cast<uint2*>(&Xl[byte]) = p;
        }
    }

    // ---- acc init = v_n[j] broadcast over rows (folds linear term into the GEMM) ----
    f32x4 acc[4][4];
    #pragma unroll
    for (int nf = 0; nf < 4; ++nf) {
        int j = wv * 64 + nf * 16 + r15;
        float vj = Wn[(size_t)j * WROW + 256] + Wn[65792 + j];
        #pragma unroll
        for (int m = 0; m < 4; ++m) acc[m][nf] = f32x4{vj, vj, vj, vj};
    }

    // ---- W staging: thread t = j; loads W[n][k0+k][j] (coalesced across t), writes B^T tile ----
    auto stageW = [&](int buf, int kk) {
        const int k0 = kk * 32;
        const int j  = tid;
        float t[32];
        #pragma unroll
        for (int k = 0; k < 32; ++k) t[k] = Wn[(size_t)(k0 + k) * WROW + j];
        char* Wb = Wl[buf];
        #pragma unroll
        for (int g = 0; g < 4; ++g) {
            unsigned int p0 = (unsigned)f2bf(t[g*8+0]) | ((unsigned)f2bf(t[g*8+1]) << 16);
            unsigned int p1 = (unsigned)f2bf(t[g*8+2]) | ((unsigned)f2bf(t[g*8+3]) << 16);
            unsigned int p2 = (unsigned)f2bf(t[g*8+4]) | ((unsigned)f2bf(t[g*8+5]) << 16);
            unsigned int p3 = (unsigned)f2bf(t[g*8+6]) | ((unsigned)f2bf(t[g*8+7]) << 16);
            int byte = (j * 64 + g * 16) ^ ((j & 7) << 4);
            *reinterpret_cast<uint4*>(&Wb[byte]) = make_uint4(p0, p1, p2, p3);
        }
    };

    auto computeK = [&](int buf, int kk) {
        char* Wb = Wl[buf];
        short8 a[4], bb[4];
        #pragma unroll
        for (int m = 0; m < 4; ++m) {
            int row = m * 16 + r15;                     // A row = lane&15
            int byte = (row * 512 + kk * 64 + qw * 16) ^ ((row & 7) << 4);
            a[m] = *reinterpret_cast<short8*>(&Xl[byte]);
        }
        #pragma unroll
        for (int nf = 0; nf < 4; ++nf) {
            int j = wv * 64 + nf * 16 + r15;            // B col = lane&15
            int byte = (j * 64 + qw * 16) ^ ((j & 7) << 4);
            bb[nf] = *reinterpret_cast<short8*>(&Wb[byte]);
        }
        #pragma unroll
        for (int m = 0; m < 4; ++m)
            #pragma unroll
            for (int nf = 0; nf < 4; ++nf)
                acc[m][nf] = __builtin_amdgcn_mfma_f32_16x16x32_bf16(a[m], bb[nf], acc[m][nf], 0, 0, 0);
    };

    stageW(0, 0);
    int cur = 0;
    #pragma unroll
    for (int kk = 0; kk < 8; ++kk) {
        __syncthreads();                 // buf[cur] ready; prev reads of buf[cur^1] done
        if (kk < 7) stageW(cur ^ 1, kk + 1);
        computeK(cur, kk);
        cur ^= 1;
    }

    // ---- fused epilogue: h[b,n] = sum_j C[b,j]*x[b,j]  (+ d_n) ----
    float ps[16];                        // [m][r]
    #pragma unroll
    for (int i = 0; i < 16; ++i) ps[i] = 0.f;
    #pragma unroll
    for (int m = 0; m < 4; ++m)
        #pragma unroll
        for (int nf = 0; nf < 4; ++nf) {
            int j = wv * 64 + nf * 16 + r15;            // C col = lane&15
            #pragma unroll
            for (int r = 0; r < 4; ++r) {
                int brow = m * 16 + qw * 4 + r;          // C row = (lane>>4)*4 + reg
                int byte = (brow * 512 + j * 2) ^ ((brow & 7) << 4);
                float xv = bf2f(*reinterpret_cast<unsigned short*>(&Xl[byte]));
                ps[m * 4 + r] += acc[m][nf][r] * xv;
            }
        }
    // reduce over the 16 j-lanes of each row-group
    #pragma unroll
    for (int off = 1; off <= 8; off <<= 1)
        #pragma unroll
        for (int i = 0; i < 16; ++i) ps[i] += __shfl_xor(ps[i], off, 64);

    __syncthreads();                     // Wl no longer needed -> reduction buffer
    float* red = reinterpret_cast<float*>(Wl);
    if (r15 == 0) {
        #pragma unroll
        for (int m = 0; m < 4; ++m)
            #pragma unroll
            for (int r = 0; r < 4; ++r)
                red[wv * 64 + m * 16 + qw * 4 + r] = ps[m * 4 + r];
    }
    __syncthreads();
    if (tid < 64) {
        float s = red[tid] + red[64 + tid] + red[128 + tid] + red[192 + tid] + Wn[66048];
        H[(size_t)(b0 + tid) * DDIM + n] = s;
    }
}

__global__ __launch_bounds__(256) void out_kernel(
    const float* __restrict__ H, const float* __restrict__ w_out,
    const float* __restrict__ b_out, float* __restrict__ out)
{
    int b = blockIdx.x * 4 + (threadIdx.x >> 6);
    int lane = threadIdx.x & 63;
    const float* h = H + (size_t)b * 256;
    float s = 0.f;
    #pragma unroll
    for (int c = 0; c < 4; ++c) s += h[lane + c * 64] * w_out[lane + c * 64];
    #pragma unroll
    for (int off = 1; off < 64; off <<= 1) s += __shfl_xor(s, off, 64);
    if (lane == 0) out[b] = s + b_out[0];
}

extern "C" void kernel_launch(void* const* d_in, const int* in_sizes, int n_in,
                              void* d_out, int out_size, void* d_ws, size_t ws_size,
                              hipStream_t stream) {
    const float* x    = (const float*)d_in[0];
    const float* W1   = (const float*)d_in[1];
    const float* W2   = (const float*)d_in[2];
    const float* W3   = (const float*)d_in[3];
    const float* wout = (const float*)d_in[4];
    const float* bout = (const float*)d_in[5];
    float* out = (float*)d_out;

    float* h1 = (float*)d_ws;            // 2048*256 f32 = 2 MB
    float* h2 = h1 + 2048 * 256;         // 2 MB
    float* h3 = h1;                      // reuse h1's slot (layer 3 reads h2)

    dim3 grid(32, 256), blk(256, 1, 1);
    pn_layer_kernel<<<grid, blk, 0, stream>>>(x,  W1, h1);
    pn_layer_kernel<<<grid, blk, 0, stream>>>(h1, W2, h2);
    pn_layer_kernel<<<grid, blk, 0, stream>>>(h2, W3, h3);
    out_kernel<<<512, blk, 0, stream>>>(h3, wout, bout, out);
}

// Round 2
// 400.667 us; speedup vs baseline: 1.4426x; 1.4426x over previous
//
#include <hip/hip_runtime.h>
#include <hip/hip_bf16.h>

typedef __attribute__((ext_vector_type(8))) short short8;   // 8 bf16 (4 VGPRs) — MFMA A/B frag
typedef __attribute__((ext_vector_type(4))) float f32x4;    // MFMA C/D frag

#define DDIM 256
#define WROW 257
#define WSTRIDE 66049  // 257*257

__device__ __forceinline__ unsigned short f2bf(float f) {
    unsigned int u = __float_as_uint(f);
    u += 0x7fff + ((u >> 16) & 1);   // RNE (finite values)
    return (unsigned short)(u >> 16);
}
__device__ __forceinline__ float bf2f(unsigned short s) {
    return __uint_as_float(((unsigned int)s) << 16);
}

// ======================= FAST PATH (needs ~38 MB ws) =======================

// Transpose+convert one 64x64 tile: Wt[n][j][k] = bf16(W[n][k][j]) for j,k<256.
__global__ __launch_bounds__(256) void conv_w_kernel(
    const float* __restrict__ Wf, unsigned short* __restrict__ Wt)
{
    __shared__ float tile[64][65];
    const int tid = threadIdx.x;
    const int n  = blockIdx.y;
    const int tj = (blockIdx.x & 3) * 64;
    const int tk = (blockIdx.x >> 2) * 64;
    const float* Wn = Wf + (size_t)n * WSTRIDE;
    #pragma unroll
    for (int it = 0; it < 16; ++it) {
        int k = it * 4 + (tid >> 6);
        int j = tid & 63;
        tile[k][j] = Wn[(size_t)(tk + k) * WROW + tj + j];   // coalesced along j
    }
    __syncthreads();
    unsigned short* out = Wt + ((size_t)n << 16);
    #pragma unroll
    for (int it = 0; it < 8; ++it) {
        int jr = it * 8 + (tid >> 5);
        int k2 = (tid & 31) * 2;
        unsigned int lo = f2bf(tile[k2][jr]);
        unsigned int hi = f2bf(tile[k2 + 1][jr]);
        *reinterpret_cast<unsigned int*>(out + (size_t)(tj + jr) * 256 + tk + k2) = lo | (hi << 16);
    }
}

// v[n][j] = W[n][j][256] + W[n][256][j]
__global__ void conv_v_kernel(const float* __restrict__ Wf, float* __restrict__ V)
{
    int n = blockIdx.x, j = threadIdx.x;
    const float* Wn = Wf + (size_t)n * WSTRIDE;
    V[n * 256 + j] = Wn[(size_t)j * WROW + 256] + Wn[65792 + j];
}

// Layer: H[b][n] = x^T A_n x + v_n.x + d_n.  BM=128 rows/block, 4 waves (wave = j-band of 64).
// B-fragments loaded straight global->reg from pre-transposed bf16 Wt (no LDS for W).
__global__ __launch_bounds__(256, 2) void pn_layer_bf_kernel(
    const float* __restrict__ X,             // [2048][256] f32
    const unsigned short* __restrict__ Wt,   // [256][256][256] bf16 (j-major)
    const float* __restrict__ V,             // [256][256]
    const float* __restrict__ Wf,            // original W (for d_n)
    float* __restrict__ H)                   // [2048][256]
{
    __shared__ __align__(16) char Xl[128 * 512];   // bf16 [128][256], XOR-swizzled, 64 KB

    const int tid  = threadIdx.x;
    const int lane = tid & 63;
    const int wv   = tid >> 6;
    const int qw   = lane >> 4;
    const int r15  = lane & 15;

    // XCD swizzle: all 16 row-tiles of one n land on one XCD, back-to-back.
    const int fid = blockIdx.y * 16 + blockIdx.x;   // hw dispatch order
    const int t   = fid >> 3;
    const int bt  = t & 15;                          // row-tile
    const int n   = (fid & 7) + 8 * (t >> 4);        // n, grouped per XCD
    const int b0  = bt * 128;

    // ---- stage X tile [128][256] f32 -> bf16 LDS (swizzle: byte ^= (row&7)<<4) ----
    {
        const float4* Xv = reinterpret_cast<const float4*>(X + (size_t)b0 * DDIM);
        #pragma unroll
        for (int it = 0; it < 32; ++it) {
            int idx4 = tid + it * 256;          // 0..8191
            int r = idx4 >> 6, c4 = idx4 & 63;
            float4 v = Xv[r * 64 + c4];
            uint2 p;
            p.x = (unsigned)f2bf(v.x) | ((unsigned)f2bf(v.y) << 16);
            p.y = (unsigned)f2bf(v.z) | ((unsigned)f2bf(v.w) << 16);
            int byte = (r * 512 + c4 * 8) ^ ((r & 7) << 4);
            *reinterpret_cast<uint2*>(&Xl[byte]) = p;
        }
    }

    // ---- acc init = v_n[j] broadcast over rows ----
    f32x4 acc[8][4];
    #pragma unroll
    for (int nf = 0; nf < 4; ++nf) {
        int j = wv * 64 + nf * 16 + r15;
        float vj = V[n * 256 + j];
        #pragma unroll
        for (int m = 0; m < 8; ++m) acc[m][nf] = f32x4{vj, vj, vj, vj};
    }

    const unsigned short* Wn = Wt + ((size_t)n << 16);
    short8 bb[2][4];
    #pragma unroll
    for (int nf = 0; nf < 4; ++nf) {
        int j = wv * 64 + nf * 16 + r15;
        bb[0][nf] = *reinterpret_cast<const short8*>(Wn + (size_t)j * 256 + qw * 8);
    }
    __syncthreads();

    // ---- K loop: 8 steps of K=32; B double-buffered in regs ----
    #pragma unroll
    for (int kk = 0; kk < 8; ++kk) {
        if (kk < 7) {
            #pragma unroll
            for (int nf = 0; nf < 4; ++nf) {
                int j = wv * 64 + nf * 16 + r15;
                bb[(kk + 1) & 1][nf] =
                    *reinterpret_cast<const short8*>(Wn + (size_t)j * 256 + (kk + 1) * 32 + qw * 8);
            }
        }
        #pragma unroll
        for (int m = 0; m < 8; ++m) {
            int row = m * 16 + r15;
            int byte = (row * 512 + kk * 64 + qw * 16) ^ ((row & 7) << 4);
            short8 a = *reinterpret_cast<short8*>(&Xl[byte]);
            #pragma unroll
            for (int nf = 0; nf < 4; ++nf)
                acc[m][nf] = __builtin_amdgcn_mfma_f32_16x16x32_bf16(a, bb[kk & 1][nf], acc[m][nf], 0, 0, 0);
        }
    }

    // ---- fused epilogue: h[b,n] = sum_j C[b,j]*x[b,j] + d_n ----
    float ps[8][4];
    #pragma unroll
    for (int m = 0; m < 8; ++m)
        #pragma unroll
        for (int r = 0; r < 4; ++r) ps[m][r] = 0.f;
    #pragma unroll
    for (int m = 0; m < 8; ++m)
        #pragma unroll
        for (int nf = 0; nf < 4; ++nf) {
            int j = wv * 64 + nf * 16 + r15;        // C col = lane&15
            #pragma unroll
            for (int r = 0; r < 4; ++r) {
                int brow = m * 16 + qw * 4 + r;      // C row = (lane>>4)*4 + reg
                int byte = (brow * 512 + j * 2) ^ ((brow & 7) << 4);
                float xv = bf2f(*reinterpret_cast<unsigned short*>(&Xl[byte]));
                ps[m][r] += acc[m][nf][r] * xv;
            }
        }
    #pragma unroll
    for (int off = 1; off <= 8; off <<= 1)
        #pragma unroll
        for (int m = 0; m < 8; ++m)
            #pragma unroll
            for (int r = 0; r < 4; ++r) ps[m][r] += __shfl_xor(ps[m][r], off, 64);

    __syncthreads();
    float* red = reinterpret_cast<float*>(Xl);
    if (r15 == 0) {
        #pragma unroll
        for (int m = 0; m < 8; ++m)
            #pragma unroll
            for (int r = 0; r < 4; ++r)
                red[wv * 128 + m * 16 + qw * 4 + r] = ps[m][r];
    }
    __syncthreads();
    if (tid < 128) {
        float d = Wf[(size_t)n * WSTRIDE + 66048];
        float s = red[tid] + red[128 + tid] + red[256 + tid] + red[384 + tid] + d;
        H[(size_t)(b0 + tid) * DDIM + n] = s;
    }
}

// ======================= FALLBACK PATH (small ws) =======================

__global__ __launch_bounds__(256, 2) void pn_layer_kernel(
    const float* __restrict__ X, const float* __restrict__ W, float* __restrict__ H)
{
    __shared__ __align__(16) char Xl[64 * 256 * 2];
    __shared__ __align__(16) char Wl[2][256 * 32 * 2];
    const int tid  = threadIdx.x;
    const int lane = tid & 63;
    const int wv   = tid >> 6;
    const int qw   = lane >> 4;
    const int r15  = lane & 15;
    const int n  = blockIdx.y;
    const int b0 = blockIdx.x * 64;
    const float* Wn = W + (size_t)n * WSTRIDE;
    {
        const float4* Xv = reinterpret_cast<const float4*>(X + (size_t)b0 * DDIM);
        #pragma unroll
        for (int it = 0; it < 16; ++it) {
            int idx4 = tid + it * 256;
            int r = idx4 >> 6, c4 = idx4 & 63;
            float4 v = Xv[r * 64 + c4];
            uint2 p;
            p.x = (unsigned)f2bf(v.x) | ((unsigned)f2bf(v.y) << 16);
            p.y = (unsigned)f2bf(v.z) | ((unsigned)f2bf(v.w) << 16);
            int byte = (r * 512 + c4 * 8) ^ ((r & 7) << 4);
            *reinterpret_cast<uint2*>(&Xl[byte]) = p;
        }
    }
    f32x4 acc[4][4];
    #pragma unroll
    for (int nf = 0; nf < 4; ++nf) {
        int j = wv * 64 + nf * 16 + r15;
        float vj = Wn[(size_t)j * WROW + 256] + Wn[65792 + j];
        #pragma unroll
        for (int m = 0; m < 4; ++m) acc[m][nf] = f32x4{vj, vj, vj, vj};
    }
    auto stageW = [&](int buf, int kk) {
        const int k0 = kk * 32;
        const int j  = tid;
        float t[32];
        #pragma unroll
        for (int k = 0; k < 32; ++k) t[k] = Wn[(size_t)(k0 + k) * WROW + j];
        char* Wb = Wl[buf];
        #pragma unroll
        for (int g = 0; g < 4; ++g) {
            unsigned int p0 = (unsigned)f2bf(t[g*8+0]) | ((unsigned)f2bf(t[g*8+1]) << 16);
            unsigned int p1 = (unsigned)f2bf(t[g*8+2]) | ((unsigned)f2bf(t[g*8+3]) << 16);
            unsigned int p2 = (unsigned)f2bf(t[g*8+4]) | ((unsigned)f2bf(t[g*8+5]) << 16);
            unsigned int p3 = (unsigned)f2bf(t[g*8+6]) | ((unsigned)f2bf(t[g*8+7]) << 16);
            int byte = (j * 64 + g * 16) ^ ((j & 7) << 4);
            *reinterpret_cast<uint4*>(&Wb[byte]) = make_uint4(p0, p1, p2, p3);
        }
    };
    auto computeK = [&](int buf, int kk) {
        char* Wb = Wl[buf];
        short8 a[4], bb[4];
        #pragma unroll
        for (int m = 0; m < 4; ++m) {
            int row = m * 16 + r15;
            int byte = (row * 512 + kk * 64 + qw * 16) ^ ((row & 7) << 4);
            a[m] = *reinterpret_cast<short8*>(&Xl[byte]);
        }
        #pragma unroll
        for (int nf = 0; nf < 4; ++nf) {
            int j = wv * 64 + nf * 16 + r15;
            int byte = (j * 64 + qw * 16) ^ ((j & 7) << 4);
            bb[nf] = *reinterpret_cast<short8*>(&Wb[byte]);
        }
        #pragma unroll
        for (int m = 0; m < 4; ++m)
            #pragma unroll
            for (int nf = 0; nf < 4; ++nf)
                acc[m][nf] = __builtin_amdgcn_mfma_f32_16x16x32_bf16(a[m], bb[nf], acc[m][nf], 0, 0, 0);
    };
    stageW(0, 0);
    int cur = 0;
    #pragma unroll
    for (int kk = 0; kk < 8; ++kk) {
        __syncthreads();
        if (kk < 7) stageW(cur ^ 1, kk + 1);
        computeK(cur, kk);
        cur ^= 1;
    }
    float ps[16];
    #pragma unroll
    for (int i = 0; i < 16; ++i) ps[i] = 0.f;
    #pragma unroll
    for (int m = 0; m < 4; ++m)
        #pragma unroll
        for (int nf = 0; nf < 4; ++nf) {
            int j = wv * 64 + nf * 16 + r15;
            #pragma unroll
            for (int r = 0; r < 4; ++r) {
                int brow = m * 16 + qw * 4 + r;
                int byte = (brow * 512 + j * 2) ^ ((brow & 7) << 4);
                float xv = bf2f(*reinterpret_cast<unsigned short*>(&Xl[byte]));
                ps[m * 4 + r] += acc[m][nf][r] * xv;
            }
        }
    #pragma unroll
    for (int off = 1; off <= 8; off <<= 1)
        #pragma unroll
        for (int i = 0; i < 16; ++i) ps[i] += __shfl_xor(ps[i], off, 64);
    __syncthreads();
    float* red = reinterpret_cast<float*>(Wl);
    if (r15 == 0) {
        #pragma unroll
        for (int m = 0; m < 4; ++m)
            #pragma unroll
            for (int r = 0; r < 4; ++r)
                red[wv * 64 + m * 16 + qw * 4 + r] = ps[m * 4 + r];
    }
    __syncthreads();
    if (tid < 64) {
        float s = red[tid] + red[64 + tid] + red[128 + tid] + red[192 + tid] + Wn[66048];
        H[(size_t)(b0 + tid) * DDIM + n] = s;
    }
}

__global__ __launch_bounds__(256) void out_kernel(
    const float* __restrict__ H, const float* __restrict__ w_out,
    const float* __restrict__ b_out, float* __restrict__ out)
{
    int b = blockIdx.x * 4 + (threadIdx.x >> 6);
    int lane = threadIdx.x & 63;
    const float* h = H + (size_t)b * 256;
    float s = 0.f;
    #pragma unroll
    for (int c = 0; c < 4; ++c) s += h[lane + c * 64] * w_out[lane + c * 64];
    #pragma unroll
    for (int off = 1; off < 64; off <<= 1) s += __shfl_xor(s, off, 64);
    if (lane == 0) out[b] = s + b_out[0];
}

extern "C" void kernel_launch(void* const* d_in, const int* in_sizes, int n_in,
                              void* d_out, int out_size, void* d_ws, size_t ws_size,
                              hipStream_t stream) {
    const float* x    = (const float*)d_in[0];
    const float* W1   = (const float*)d_in[1];
    const float* W2   = (const float*)d_in[2];
    const float* W3   = (const float*)d_in[3];
    const float* wout = (const float*)d_in[4];
    const float* bout = (const float*)d_in[5];
    float* out = (float*)d_out;

    const size_t WT_BYTES = (size_t)256 * 256 * 256 * 2;   // 33.55 MB
    const size_t V_BYTES  = 256 * 256 * 4;                 // 256 KB
    const size_t H_BYTES  = (size_t)2048 * 256 * 4;        // 2 MB
    const size_t need = WT_BYTES + V_BYTES + 2 * H_BYTES;

    dim3 blk(256, 1, 1);

    if (ws_size >= need) {
        unsigned short* Wt = (unsigned short*)d_ws;
        float* V  = (float*)((char*)d_ws + WT_BYTES);
        float* h1 = (float*)((char*)d_ws + WT_BYTES + V_BYTES);
        float* h2 = h1 + 2048 * 256;

        const float* Ws[3]   = {W1, W2, W3};
        const float* Xin[3]  = {x, h1, h2};
        float*       Hout[3] = {h1, h2, h1};

        dim3 cgrid(16, 256), lgrid(16, 256);
        for (int L = 0; L < 3; ++L) {
            conv_w_kernel<<<cgrid, blk, 0, stream>>>(Ws[L], Wt);
            conv_v_kernel<<<dim3(256), blk, 0, stream>>>(Ws[L], V);
            pn_layer_bf_kernel<<<lgrid, blk, 0, stream>>>(Xin[L], Wt, V, Ws[L], Hout[L]);
        }
        out_kernel<<<512, blk, 0, stream>>>(h1, wout, bout, out);
    } else {
        float* h1 = (float*)d_ws;
        float* h2 = h1 + 2048 * 256;
        dim3 grid(32, 256);
        pn_layer_kernel<<<grid, blk, 0, stream>>>(x,  W1, h1);
        pn_layer_kernel<<<grid, blk, 0, stream>>>(h1, W2, h2);
        pn_layer_kernel<<<grid, blk, 0, stream>>>(h2, W3, h1);
        out_kernel<<<512, blk, 0, stream>>>(h1, wout, bout, out);
    }
}